// Round 1
// baseline (3422.981 us; speedup 1.0000x reference)
//
#include <hip/hip_runtime.h>

#define N_NODES 50000
#define N_EDGES 800000
#define D_IN    128
#define D_E     64
#define NH      4
#define F_TOT   128          // NH * D_OUT
#define NEG_SLOPE 0.2f

// ---------------------------------------------------------------------------
// K1: HT[n][f] = sum_k H[n][k] * W[f][k]        (HT -> workspace, fp32)
// 4 waves/block, 8 nodes per wave-iteration. W transposed into LDS (k-major,
// 64 KB) so per-lane reads wt[k][2l..2l+1] are contiguous (2-way alias = free).
// H rows are read as same-address float4 broadcasts (L1 serves all 64 lanes).
// ---------------------------------------------------------------------------
__global__ __launch_bounds__(256) void k_node_transform(
    const float* __restrict__ H, const float* __restrict__ W,
    float* __restrict__ HT)
{
    __shared__ float wt[D_IN * F_TOT];   // wt[k*128+f] = W[f][k]
    const int tid = threadIdx.x;
    for (int i = tid; i < D_IN * F_TOT; i += 256) {
        const int f = i & 127, k = i >> 7;
        wt[k * F_TOT + f] = W[f * D_IN + k];   // uncoalesced read, one-time; conflict-free LDS write
    }
    __syncthreads();

    const int l = tid & 63;
    const int w = tid >> 6;
    const int gwave  = blockIdx.x * 4 + w;
    const int nwaves = gridDim.x * 4;
    const int ngroups = N_NODES / 8;     // 6250, exact

    for (int grp = gwave; grp < ngroups; grp += nwaves) {
        const int g = grp * 8;
        float ax[8], ay[8];
#pragma unroll
        for (int j = 0; j < 8; ++j) { ax[j] = 0.f; ay[j] = 0.f; }

        for (int k4 = 0; k4 < D_IN / 4; ++k4) {
            float hv[8][4];
#pragma unroll
            for (int j = 0; j < 8; ++j)
                *(float4*)hv[j] = *(const float4*)&H[(size_t)(g + j) * D_IN + k4 * 4];
#pragma unroll
            for (int kk = 0; kk < 4; ++kk) {
                const float2 wk = *(const float2*)&wt[(k4 * 4 + kk) * F_TOT + 2 * l];
#pragma unroll
                for (int j = 0; j < 8; ++j) {
                    ax[j] = fmaf(wk.x, hv[j][kk], ax[j]);
                    ay[j] = fmaf(wk.y, hv[j][kk], ay[j]);
                }
            }
        }
#pragma unroll
        for (int j = 0; j < 8; ++j) {
            float2 r; r.x = ax[j]; r.y = ay[j];
            *(float2*)&HT[(size_t)(g + j) * F_TOT + 2 * l] = r;  // coalesced 512B
        }
    }
}

// ---------------------------------------------------------------------------
// K2: fused edge pass. Per edge e (8 per wave):
//   ET = W_e @ E[e]          (on the fly, W_e staged k-major in LDS, 32 KB)
//   a  = lrelu(HT[src]+HT[dst]+ET) . att   per head (shfl reduce over 16 lanes)
//   w  = exp(a)              (softmax shift skipped: mathematically invariant)
//   atomicAdd: a_sum[dst,h] += w ;  out[dst,f] += w * HT[src,f]
// Normalization by (a_sum+eps) is factored into K3.
// ---------------------------------------------------------------------------
__global__ __launch_bounds__(256) void k_edge_pass(
    const float* __restrict__ E, const int* __restrict__ EI,
    const float* __restrict__ We, const float* __restrict__ att,
    const float* __restrict__ HT,
    float* __restrict__ out, float* __restrict__ a_sum)
{
    __shared__ float wte[D_E * F_TOT];   // wte[k*128+f] = We[f][k]
    const int tid = threadIdx.x;
    for (int i = tid; i < D_E * F_TOT; i += 256) {
        const int f = i & 127, k = i >> 7;
        wte[k * F_TOT + f] = We[f * D_E + k];
    }
    __syncthreads();

    const int l = tid & 63;
    const int w = tid >> 6;
    const float2 attv = *(const float2*)&att[2 * l];   // att[f], f = 2l, 2l+1
    const int h = l >> 4;                              // head of f=2l and 2l+1
    const int gwave  = blockIdx.x * 4 + w;
    const int nwaves = gridDim.x * 4;
    const int niter  = N_EDGES / 8;      // 100000, exact

    for (int it = gwave; it < niter; it += nwaves) {
        const int eb = it * 8;
        int sj[8], dj[8];
#pragma unroll
        for (int j = 0; j < 8; ++j) {
            sj[j] = EI[eb + j];              // src row
            dj[j] = EI[N_EDGES + eb + j];    // dst row
        }
        float2 hs[8], hd[8];
#pragma unroll
        for (int j = 0; j < 8; ++j) {        // coalesced 512B gathers, L2/L3-resident
            hs[j] = *(const float2*)&HT[(size_t)sj[j] * F_TOT + 2 * l];
            hd[j] = *(const float2*)&HT[(size_t)dj[j] * F_TOT + 2 * l];
        }

        float ax[8], ay[8];
#pragma unroll
        for (int j = 0; j < 8; ++j) { ax[j] = 0.f; ay[j] = 0.f; }

        for (int k4 = 0; k4 < D_E / 4; ++k4) {
            float ev[8][4];
#pragma unroll
            for (int j = 0; j < 8; ++j)      // same-addr broadcast, E streamed once
                *(float4*)ev[j] = *(const float4*)&E[(size_t)(eb + j) * D_E + k4 * 4];
#pragma unroll
            for (int kk = 0; kk < 4; ++kk) {
                const float2 wk = *(const float2*)&wte[(k4 * 4 + kk) * F_TOT + 2 * l];
#pragma unroll
                for (int j = 0; j < 8; ++j) {
                    ax[j] = fmaf(wk.x, ev[j][kk], ax[j]);
                    ay[j] = fmaf(wk.y, ev[j][kk], ay[j]);
                }
            }
        }

#pragma unroll
        for (int j = 0; j < 8; ++j) {
            float vx = ax[j] + hs[j].x + hd[j].x;
            float vy = ay[j] + hs[j].y + hd[j].y;
            vx = vx > 0.f ? vx : NEG_SLOPE * vx;
            vy = vy > 0.f ? vy : NEG_SLOPE * vy;
            float p = fmaf(vx, attv.x, vy * attv.y);
            // reduce over the 16-lane group that owns this head's 32 features
#pragma unroll
            for (int m = 1; m < 16; m <<= 1) p += __shfl_xor(p, m, 64);
            const float wgt = __expf(p);
            atomicAdd(&out[(size_t)dj[j] * F_TOT + 2 * l],     wgt * hs[j].x);
            atomicAdd(&out[(size_t)dj[j] * F_TOT + 2 * l + 1], wgt * hs[j].y);
            if ((l & 15) == 0)
                atomicAdd(&a_sum[dj[j] * NH + h], wgt);
        }
    }
}

// ---------------------------------------------------------------------------
// K3: out[n, h*32+fo] /= (a_sum[n,h] + 1e-16)
// ---------------------------------------------------------------------------
__global__ __launch_bounds__(256) void k_normalize(
    float* __restrict__ out, const float* __restrict__ a_sum)
{
    const int i = blockIdx.x * 256 + threadIdx.x;
    if (i >= N_NODES * F_TOT) return;
    const int n = i >> 7;
    const int h = (i & 127) >> 5;
    out[i] = out[i] / (a_sum[n * NH + h] + 1e-16f);
}

extern "C" void kernel_launch(void* const* d_in, const int* in_sizes, int n_in,
                              void* d_out, int out_size, void* d_ws, size_t ws_size,
                              hipStream_t stream)
{
    const float* H   = (const float*)d_in[0];
    const int*   EI  = (const int*)d_in[1];    // edge_index: harness delivers int32
    const float* E   = (const float*)d_in[2];
    const float* W   = (const float*)d_in[3];
    const float* We  = (const float*)d_in[4];
    const float* att = (const float*)d_in[5];
    float* out = (float*)d_out;

    // workspace: HT [50000*128] f32, then a_sum [50000*4] f32  (~26.4 MB)
    float* HT    = (float*)d_ws;
    float* a_sum = (float*)((char*)d_ws + (size_t)N_NODES * F_TOT * sizeof(float));

    hipMemsetAsync(d_out, 0, (size_t)N_NODES * F_TOT * sizeof(float), stream);
    hipMemsetAsync(a_sum, 0, (size_t)N_NODES * NH * sizeof(float), stream);

    k_node_transform<<<512, 256, 0, stream>>>(H, W, HT);
    k_edge_pass<<<1024, 256, 0, stream>>>(E, EI, We, att, HT, out, a_sum);
    k_normalize<<<(N_NODES * F_TOT + 255) / 256, 256, 0, stream>>>(out, a_sum);
}

// Round 2
// 1437.908 us; speedup vs baseline: 2.3805x; 2.3805x over previous
//
#include <hip/hip_runtime.h>

#define N_NODES 50000
#define N_EDGES 800000
#define D_IN    128
#define D_E     64
#define NH      4
#define F_TOT   128          // NH * D_OUT
#define NEG_SLOPE 0.2f

// ---------------------------------------------------------------------------
// K1: HT[n][f] = sum_k H[n][k] * W[f][k]   (fp32, -> workspace)
// ---------------------------------------------------------------------------
__global__ __launch_bounds__(256) void k_node_transform(
    const float* __restrict__ H, const float* __restrict__ W,
    float* __restrict__ HT)
{
    __shared__ float wt[D_IN * F_TOT];   // wt[k*128+f] = W[f][k]
    const int tid = threadIdx.x;
    for (int i = tid; i < D_IN * F_TOT; i += 256) {
        const int f = i & 127, k = i >> 7;
        wt[k * F_TOT + f] = W[f * D_IN + k];
    }
    __syncthreads();

    const int l = tid & 63;
    const int w = tid >> 6;
    const int gwave  = blockIdx.x * 4 + w;
    const int nwaves = gridDim.x * 4;
    const int ngroups = N_NODES / 8;     // 6250, exact

    for (int grp = gwave; grp < ngroups; grp += nwaves) {
        const int g = grp * 8;
        float ax[8], ay[8];
#pragma unroll
        for (int j = 0; j < 8; ++j) { ax[j] = 0.f; ay[j] = 0.f; }

        for (int k4 = 0; k4 < D_IN / 4; ++k4) {
            float hv[8][4];
#pragma unroll
            for (int j = 0; j < 8; ++j)
                *(float4*)hv[j] = *(const float4*)&H[(size_t)(g + j) * D_IN + k4 * 4];
#pragma unroll
            for (int kk = 0; kk < 4; ++kk) {
                const float2 wk = *(const float2*)&wt[(k4 * 4 + kk) * F_TOT + 2 * l];
#pragma unroll
                for (int j = 0; j < 8; ++j) {
                    ax[j] = fmaf(wk.x, hv[j][kk], ax[j]);
                    ay[j] = fmaf(wk.y, hv[j][kk], ay[j]);
                }
            }
        }
#pragma unroll
        for (int j = 0; j < 8; ++j) {
            float2 r; r.x = ax[j]; r.y = ay[j];
            *(float2*)&HT[(size_t)(g + j) * F_TOT + 2 * l] = r;
        }
    }
}

// ---------------------------------------------------------------------------
// K2a: histogram of dst degrees
// ---------------------------------------------------------------------------
__global__ __launch_bounds__(256) void k_hist(
    const int* __restrict__ EI, int* __restrict__ deg)
{
    const int e = blockIdx.x * 256 + threadIdx.x;
    if (e < N_EDGES) atomicAdd(&deg[EI[N_EDGES + e]], 1);
}

// ---------------------------------------------------------------------------
// K2b: single-block exclusive scan of deg -> row_start[0..N], cursor copy
// ---------------------------------------------------------------------------
__global__ __launch_bounds__(1024) void k_scan(
    const int* __restrict__ deg, int* __restrict__ row_start,
    int* __restrict__ cursor)
{
    __shared__ int wsum[16];
    __shared__ int carry;
    const int tid = threadIdx.x;
    const int l = tid & 63;
    const int wv = tid >> 6;
    if (tid == 0) carry = 0;

    for (int base = 0; base < N_NODES; base += 1024) {
        __syncthreads();                       // [A] carry ready, wsum free
        const int cb = carry;
        const int i = base + tid;
        const int v = (i < N_NODES) ? deg[i] : 0;
        int x = v;                             // inclusive wave scan
#pragma unroll
        for (int off = 1; off < 64; off <<= 1) {
            int t = __shfl_up(x, off, 64);
            if (l >= off) x += t;
        }
        if (l == 63) wsum[wv] = x;
        __syncthreads();                       // [B] wsum ready
        int wave_off = 0;
        for (int k = 0; k < wv; ++k) wave_off += wsum[k];
        int tot = 0;
#pragma unroll
        for (int k = 0; k < 16; ++k) tot += wsum[k];
        const int excl = cb + wave_off + (x - v);
        if (i < N_NODES) { row_start[i] = excl; cursor[i] = excl; }
        __syncthreads();                       // [C] all read cb/wsum
        if (tid == 0) carry = cb + tot;
    }
    __syncthreads();
    if (tid == 0) row_start[N_NODES] = carry;
}

// ---------------------------------------------------------------------------
// K3: Phase A — per-edge attention weight, written in CSR(dst) order.
//   ET = W_e @ E[e] on the fly (W_e k-major in LDS, 32 KB)
//   p  = sum_f lrelu(HT[src]+HT[dst]+ET)[f] * att[f]  per head (16-lane shfl)
//   w  = exp(p)   (softmax shift skipped: shift-invariant, logits bounded)
//   pos = atomicAdd(cursor[dst], 1)  -- ONE atomic per edge
//   wperm[4*pos+h] = w ; srcperm[pos] = src
// ---------------------------------------------------------------------------
__global__ __launch_bounds__(256) void k_edge_weights(
    const float* __restrict__ E, const int* __restrict__ EI,
    const float* __restrict__ We, const float* __restrict__ att,
    const float* __restrict__ HT,
    float* __restrict__ wperm, int* __restrict__ srcperm,
    int* __restrict__ cursor)
{
    __shared__ float wte[D_E * F_TOT];   // wte[k*128+f] = We[f][k]
    const int tid = threadIdx.x;
    for (int i = tid; i < D_E * F_TOT; i += 256) {
        const int f = i & 127, k = i >> 7;
        wte[k * F_TOT + f] = We[f * D_E + k];
    }
    __syncthreads();

    const int l = tid & 63;
    const int wv = tid >> 6;
    const float2 attv = *(const float2*)&att[2 * l];
    const int h = l >> 4;
    const int gwave  = blockIdx.x * 4 + wv;
    const int nwaves = gridDim.x * 4;
    const int niter  = N_EDGES / 4;      // 200000, exact

    for (int it = gwave; it < niter; it += nwaves) {
        const int eb = it * 4;
        int sj[4], dj[4];
#pragma unroll
        for (int j = 0; j < 4; ++j) {
            sj[j] = EI[eb + j];
            dj[j] = EI[N_EDGES + eb + j];
        }
        float2 hs[4], hd[4];
#pragma unroll
        for (int j = 0; j < 4; ++j) {
            hs[j] = *(const float2*)&HT[(size_t)sj[j] * F_TOT + 2 * l];
            hd[j] = *(const float2*)&HT[(size_t)dj[j] * F_TOT + 2 * l];
        }

        float ax[4], ay[4];
#pragma unroll
        for (int j = 0; j < 4; ++j) { ax[j] = 0.f; ay[j] = 0.f; }

        for (int k4 = 0; k4 < D_E / 4; ++k4) {
            float ev[4][4];
#pragma unroll
            for (int j = 0; j < 4; ++j)      // wave-uniform addr -> broadcast
                *(float4*)ev[j] = *(const float4*)&E[(size_t)(eb + j) * D_E + k4 * 4];
#pragma unroll
            for (int kk = 0; kk < 4; ++kk) {
                const float2 wk = *(const float2*)&wte[(k4 * 4 + kk) * F_TOT + 2 * l];
#pragma unroll
                for (int j = 0; j < 4; ++j) {
                    ax[j] = fmaf(wk.x, ev[j][kk], ax[j]);
                    ay[j] = fmaf(wk.y, ev[j][kk], ay[j]);
                }
            }
        }

#pragma unroll
        for (int j = 0; j < 4; ++j) {
            float vx = ax[j] + hs[j].x + hd[j].x;
            float vy = ay[j] + hs[j].y + hd[j].y;
            vx = vx > 0.f ? vx : NEG_SLOPE * vx;
            vy = vy > 0.f ? vy : NEG_SLOPE * vy;
            float p = fmaf(vx, attv.x, vy * attv.y);
#pragma unroll
            for (int m = 1; m < 16; m <<= 1) p += __shfl_xor(p, m, 64);
            const float wgt = __expf(p);
            int pos = 0;
            if (l == 0) pos = atomicAdd(&cursor[dj[j]], 1);
            pos = __shfl(pos, 0, 64);
            if ((l & 15) == 0) wperm[4 * pos + h] = wgt;
            if (l == 0) srcperm[pos] = sj[j];
        }
    }
}

// ---------------------------------------------------------------------------
// K4: Phase B — one wave per dst node: sequential walk of its CSR slice,
// gather HT[src] rows, accumulate, normalize, single coalesced store.
// ---------------------------------------------------------------------------
__global__ __launch_bounds__(256) void k_aggregate(
    const float* __restrict__ HT, const float* __restrict__ wperm,
    const int* __restrict__ srcperm, const int* __restrict__ row_start,
    float* __restrict__ out)
{
    const int tid = threadIdx.x;
    const int l = tid & 63;
    const int wv = tid >> 6;
    const int n = blockIdx.x * 4 + wv;
    if (n >= N_NODES) return;
    const int h = l >> 4;
    const int beg = row_start[n];
    const int end = row_start[n + 1];

    float accx = 0.f, accy = 0.f, sw = 0.f;
    int p = beg;
    // unroll-2 for load ILP
    for (; p + 1 < end; p += 2) {
        const int s0 = srcperm[p];
        const int s1 = srcperm[p + 1];
        const float w0 = wperm[4 * p + h];
        const float w1 = wperm[4 * (p + 1) + h];
        const float2 h0 = *(const float2*)&HT[(size_t)s0 * F_TOT + 2 * l];
        const float2 h1 = *(const float2*)&HT[(size_t)s1 * F_TOT + 2 * l];
        accx = fmaf(w0, h0.x, accx); accy = fmaf(w0, h0.y, accy);
        accx = fmaf(w1, h1.x, accx); accy = fmaf(w1, h1.y, accy);
        sw += w0 + w1;
    }
    if (p < end) {
        const int s0 = srcperm[p];
        const float w0 = wperm[4 * p + h];
        const float2 h0 = *(const float2*)&HT[(size_t)s0 * F_TOT + 2 * l];
        accx = fmaf(w0, h0.x, accx); accy = fmaf(w0, h0.y, accy);
        sw += w0;
    }
    const float inv = 1.f / (sw + 1e-16f);
    float2 r; r.x = accx * inv; r.y = accy * inv;
    *(float2*)&out[(size_t)n * F_TOT + 2 * l] = r;
}

extern "C" void kernel_launch(void* const* d_in, const int* in_sizes, int n_in,
                              void* d_out, int out_size, void* d_ws, size_t ws_size,
                              hipStream_t stream)
{
    const float* H   = (const float*)d_in[0];
    const int*   EI  = (const int*)d_in[1];
    const float* E   = (const float*)d_in[2];
    const float* W   = (const float*)d_in[3];
    const float* We  = (const float*)d_in[4];
    const float* att = (const float*)d_in[5];
    float* out = (float*)d_out;

    // workspace layout (~42.2 MB)
    float* HT        = (float*)d_ws;                       // 6.4M f32
    float* wperm     = HT + (size_t)N_NODES * F_TOT;       // 3.2M f32
    int*   srcperm   = (int*)(wperm + (size_t)N_EDGES * NH); // 800k i32
    int*   deg       = srcperm + N_EDGES;                  // 50k
    int*   row_start = deg + N_NODES;                      // 50k+1
    int*   cursor    = row_start + N_NODES + 1;            // 50k

    hipMemsetAsync(deg, 0, N_NODES * sizeof(int), stream);

    k_hist<<<(N_EDGES + 255) / 256, 256, 0, stream>>>(EI, deg);
    k_scan<<<1, 1024, 0, stream>>>(deg, row_start, cursor);
    k_node_transform<<<512, 256, 0, stream>>>(H, W, HT);
    k_edge_weights<<<2048, 256, 0, stream>>>(E, EI, We, att, HT,
                                             wperm, srcperm, cursor);
    k_aggregate<<<(N_NODES + 3) / 4, 256, 0, stream>>>(HT, wperm, srcperm,
                                                       row_start, out);
}

// Round 3
// 687.327 us; speedup vs baseline: 4.9801x; 2.0920x over previous
//
#include <hip/hip_runtime.h>

#define N_NODES 50000
#define N_EDGES 800000
#define D_IN    128
#define D_E     64
#define NH      4
#define F_TOT   128          // NH * D_OUT
#define NEG_SLOPE 0.2f

typedef __attribute__((ext_vector_type(8))) short short8;   // 8 bf16
typedef __attribute__((ext_vector_type(4))) float f32x4;

__device__ __forceinline__ short f2bf(float x) {            // RNE f32->bf16
    unsigned u = __float_as_uint(x);
    u += 0x7FFFu + ((u >> 16) & 1u);
    return (short)(u >> 16);
}

// ---------------------------------------------------------------------------
// K1: HT[n][f] = sum_k H[n][k] * W[f][k]   (fp32, -> workspace)
// kept fp32: HT feeds the output directly; accuracy budget spent on ET only.
// ---------------------------------------------------------------------------
__global__ __launch_bounds__(256) void k_node_transform(
    const float* __restrict__ H, const float* __restrict__ W,
    float* __restrict__ HT)
{
    __shared__ float wt[D_IN * F_TOT];   // wt[k*128+f] = W[f][k]
    const int tid = threadIdx.x;
    for (int i = tid; i < D_IN * F_TOT; i += 256) {
        const int f = i & 127, k = i >> 7;
        wt[k * F_TOT + f] = W[f * D_IN + k];
    }
    __syncthreads();

    const int l = tid & 63;
    const int w = tid >> 6;
    const int gwave  = blockIdx.x * 4 + w;
    const int nwaves = gridDim.x * 4;
    const int ngroups = N_NODES / 8;     // 6250, exact

    for (int grp = gwave; grp < ngroups; grp += nwaves) {
        const int g = grp * 8;
        float ax[8], ay[8];
#pragma unroll
        for (int j = 0; j < 8; ++j) { ax[j] = 0.f; ay[j] = 0.f; }

        for (int k4 = 0; k4 < D_IN / 4; ++k4) {
            float hv[8][4];
#pragma unroll
            for (int j = 0; j < 8; ++j)
                *(float4*)hv[j] = *(const float4*)&H[(size_t)(g + j) * D_IN + k4 * 4];
#pragma unroll
            for (int kk = 0; kk < 4; ++kk) {
                const float2 wk = *(const float2*)&wt[(k4 * 4 + kk) * F_TOT + 2 * l];
#pragma unroll
                for (int j = 0; j < 8; ++j) {
                    ax[j] = fmaf(wk.x, hv[j][kk], ax[j]);
                    ay[j] = fmaf(wk.y, hv[j][kk], ay[j]);
                }
            }
        }
#pragma unroll
        for (int j = 0; j < 8; ++j) {
            float2 r; r.x = ax[j]; r.y = ay[j];
            *(float2*)&HT[(size_t)(g + j) * F_TOT + 2 * l] = r;
        }
    }
}

// ---------------------------------------------------------------------------
// K2a: histogram of dst degrees
// ---------------------------------------------------------------------------
__global__ __launch_bounds__(256) void k_hist(
    const int* __restrict__ EI, int* __restrict__ deg)
{
    const int e = blockIdx.x * 256 + threadIdx.x;
    if (e < N_EDGES) atomicAdd(&deg[EI[N_EDGES + e]], 1);
}

// ---------------------------------------------------------------------------
// K2b: single-block exclusive scan of deg -> row_start[0..N], cursor copy
// ---------------------------------------------------------------------------
__global__ __launch_bounds__(1024) void k_scan(
    const int* __restrict__ deg, int* __restrict__ row_start,
    int* __restrict__ cursor)
{
    __shared__ int wsum[16];
    __shared__ int carry;
    const int tid = threadIdx.x;
    const int l = tid & 63;
    const int wv = tid >> 6;
    if (tid == 0) carry = 0;

    for (int base = 0; base < N_NODES; base += 1024) {
        __syncthreads();                       // [A] carry ready, wsum free
        const int cb = carry;
        const int i = base + tid;
        const int v = (i < N_NODES) ? deg[i] : 0;
        int x = v;                             // inclusive wave scan
#pragma unroll
        for (int off = 1; off < 64; off <<= 1) {
            int t = __shfl_up(x, off, 64);
            if (l >= off) x += t;
        }
        if (l == 63) wsum[wv] = x;
        __syncthreads();                       // [B] wsum ready
        int wave_off = 0;
        for (int k = 0; k < wv; ++k) wave_off += wsum[k];
        int tot = 0;
#pragma unroll
        for (int k = 0; k < 16; ++k) tot += wsum[k];
        const int excl = cb + wave_off + (x - v);
        if (i < N_NODES) { row_start[i] = excl; cursor[i] = excl; }
        __syncthreads();                       // [C] all read cb/wsum
        if (tid == 0) carry = cb + tot;
    }
    __syncthreads();
    if (tid == 0) row_start[N_NODES] = carry;
}

// ---------------------------------------------------------------------------
// K3: MFMA logit kernel. One wave processes a tile of 16 edges:
//   ET(16x128) = E_tile(16x64) @ We^T(64x128) via 16x mfma_f32_16x16x32_bf16
//     A-frag: A[m=lane&15][k=(lane>>4)*8+j]  (verified layout)
//     B-frag: B[k][n=lane&15], k=(lane>>4)*8+j  -> b[j]=We[n][k] (We row-major)
//     C/D:    col=lane&15 (feature), row=(lane>>4)*4+reg (edge)   (verified)
//   logit p[h] = sum_f lrelu(HT[src]+HT[dst]+ET)[f]*att[f]; w = exp(p)
//   CSR scatter: pos = atomicAdd(cursor[dst],1); wperm[4pos+h]=w; srcperm[pos]=src
// ---------------------------------------------------------------------------
__global__ __launch_bounds__(256, 3) void k_logits(
    const float* __restrict__ E, const int* __restrict__ EI,
    const float* __restrict__ We, const float* __restrict__ att,
    const float* __restrict__ HT,
    float* __restrict__ wperm, int* __restrict__ srcperm,
    int* __restrict__ cursor)
{
    const int tid = threadIdx.x;
    const int l   = tid & 63;
    const int wv  = tid >> 6;
    const int r16 = l & 15;          // A: edge row   B: feature col   D: feature col
    const int g4  = l >> 4;          // k-chunk selector / D row group

    // register-resident B fragments: bf[ft][kc][j] = We[ft*16+r16][kc*32+g4*8+j]
    short8 bf[8][2];
#pragma unroll
    for (int ft = 0; ft < 8; ++ft) {
#pragma unroll
        for (int kc = 0; kc < 2; ++kc) {
            const float* wp = &We[(size_t)(ft * 16 + r16) * D_E + kc * 32 + g4 * 8];
            const float4 lo = *(const float4*)wp;
            const float4 hi = *(const float4*)(wp + 4);
            short8 b;
            b[0] = f2bf(lo.x); b[1] = f2bf(lo.y); b[2] = f2bf(lo.z); b[3] = f2bf(lo.w);
            b[4] = f2bf(hi.x); b[5] = f2bf(hi.y); b[6] = f2bf(hi.z); b[7] = f2bf(hi.w);
            bf[ft][kc] = b;
        }
    }
    float attv[8];
#pragma unroll
    for (int ft = 0; ft < 8; ++ft) attv[ft] = att[ft * 16 + r16];

    const int gwave  = blockIdx.x * 4 + wv;
    const int nwaves = gridDim.x * 4;
    const int ntiles = N_EDGES / 16;     // 50000, exact

    for (int t = gwave; t < ntiles; t += nwaves) {
        const int e0 = t * 16;
        // A fragments from E (f32 -> bf16)
        short8 af[2];
#pragma unroll
        for (int kc = 0; kc < 2; ++kc) {
            const float* ep = &E[(size_t)(e0 + r16) * D_E + kc * 32 + g4 * 8];
            const float4 lo = *(const float4*)ep;
            const float4 hi = *(const float4*)(ep + 4);
            short8 a;
            a[0] = f2bf(lo.x); a[1] = f2bf(lo.y); a[2] = f2bf(lo.z); a[3] = f2bf(lo.w);
            a[4] = f2bf(hi.x); a[5] = f2bf(hi.y); a[6] = f2bf(hi.z); a[7] = f2bf(hi.w);
            af[kc] = a;
        }
        f32x4 acc[8];
#pragma unroll
        for (int ft = 0; ft < 8; ++ft) {
            f32x4 z = {0.f, 0.f, 0.f, 0.f};
            z = __builtin_amdgcn_mfma_f32_16x16x32_bf16(af[0], bf[ft][0], z, 0, 0, 0);
            acc[ft] = __builtin_amdgcn_mfma_f32_16x16x32_bf16(af[1], bf[ft][1], z, 0, 0, 0);
        }
        // src/dst for this group's 4 edges (rows g4*4+r)
        int sr_[4], dr_[4];
#pragma unroll
        for (int r = 0; r < 4; ++r) {
            sr_[r] = EI[e0 + g4 * 4 + r];
            dr_[r] = EI[N_EDGES + e0 + g4 * 4 + r];
        }
#pragma unroll
        for (int r = 0; r < 4; ++r) {
            const int sr = sr_[r], dr = dr_[r];
            float ph[4] = {0.f, 0.f, 0.f, 0.f};
#pragma unroll
            for (int ft = 0; ft < 8; ++ft) {
                const float hs = HT[(size_t)sr * F_TOT + ft * 16 + r16];
                const float hd = HT[(size_t)dr * F_TOT + ft * 16 + r16];
                float v = hs + hd + acc[ft][r];
                v = v > 0.f ? v : NEG_SLOPE * v;
                ph[ft >> 1] = fmaf(v, attv[ft], ph[ft >> 1]);
            }
            // reduce over the 16 lanes (feature cols) of this group
#pragma unroll
            for (int m = 1; m < 16; m <<= 1) {
#pragma unroll
                for (int hh = 0; hh < 4; ++hh)
                    ph[hh] += __shfl_xor(ph[hh], m, 64);
            }
            const float w0 = __expf(ph[0]), w1 = __expf(ph[1]);
            const float w2 = __expf(ph[2]), w3 = __expf(ph[3]);
            int pos = 0;
            if (r16 == 0) pos = atomicAdd(&cursor[dr], 1);
            pos = __shfl(pos, l & 48, 64);        // broadcast from lane g4*16
            if (r16 < 4) {
                const float wv_ = r16 == 0 ? w0 : r16 == 1 ? w1 : r16 == 2 ? w2 : w3;
                wperm[4 * pos + r16] = wv_;
            }
            if (r16 == 4) srcperm[pos] = sr;
        }
    }
}

// ---------------------------------------------------------------------------
// K4: aggregation. One wave per dst node; per 16-edge batch, ONE coalesced
// preload of srcperm (lanes 0-15) and wperm (all 64 lanes), distributed by
// shfl; 16 fully-unrolled independent HT[src] gathers in flight.
// ---------------------------------------------------------------------------
__global__ __launch_bounds__(256, 8) void k_aggregate(
    const float* __restrict__ HT, const float* __restrict__ wperm,
    const int* __restrict__ srcperm, const int* __restrict__ row_start,
    float* __restrict__ out)
{
    const int tid = threadIdx.x;
    const int l = tid & 63;
    const int wv = tid >> 6;
    const int n = blockIdx.x * 4 + wv;
    if (n >= N_NODES) return;
    const int h = l >> 4;
    const int beg = row_start[n];
    const int end = row_start[n + 1];

    float ax = 0.f, ay = 0.f, sw = 0.f;
    for (int base = beg; base < end; base += 16) {
        const int   svl = (l < 16 && base + l < end) ? srcperm[base + l] : 0;
        const float wvl = (4 * base + l < 4 * end) ? wperm[4 * base + l] : 0.f;
#pragma unroll
        for (int j = 0; j < 16; ++j) {
            const int   s = __shfl(svl, j, 64);
            const float w = __shfl(wvl, 4 * j + h, 64);
            const float2 hs = *(const float2*)&HT[(size_t)s * F_TOT + 2 * l];
            ax = fmaf(w, hs.x, ax);
            ay = fmaf(w, hs.y, ay);
            sw += w;                  // w==0 for padded slots
        }
    }
    const float inv = 1.f / (sw + 1e-16f);
    float2 r; r.x = ax * inv; r.y = ay * inv;
    *(float2*)&out[(size_t)n * F_TOT + 2 * l] = r;
}

extern "C" void kernel_launch(void* const* d_in, const int* in_sizes, int n_in,
                              void* d_out, int out_size, void* d_ws, size_t ws_size,
                              hipStream_t stream)
{
    const float* H   = (const float*)d_in[0];
    const int*   EI  = (const int*)d_in[1];
    const float* E   = (const float*)d_in[2];
    const float* W   = (const float*)d_in[3];
    const float* We  = (const float*)d_in[4];
    const float* att = (const float*)d_in[5];
    float* out = (float*)d_out;

    // workspace layout (~42.2 MB)
    float* HT        = (float*)d_ws;                          // 6.4M f32
    float* wperm     = HT + (size_t)N_NODES * F_TOT;          // 3.2M f32
    int*   srcperm   = (int*)(wperm + (size_t)N_EDGES * NH);  // 800k i32
    int*   deg       = srcperm + N_EDGES;                     // 50k
    int*   row_start = deg + N_NODES;                         // 50k+1
    int*   cursor    = row_start + N_NODES + 1;               // 50k

    hipMemsetAsync(deg, 0, N_NODES * sizeof(int), stream);

    k_hist<<<(N_EDGES + 255) / 256, 256, 0, stream>>>(EI, deg);
    k_scan<<<1, 1024, 0, stream>>>(deg, row_start, cursor);
    k_node_transform<<<512, 256, 0, stream>>>(H, W, HT);
    k_logits<<<1024, 256, 0, stream>>>(E, EI, We, att, HT,
                                       wperm, srcperm, cursor);
    k_aggregate<<<(N_NODES + 3) / 4, 256, 0, stream>>>(HT, wperm, srcperm,
                                                       row_start, out);
}